// Round 2
// baseline (467.954 us; speedup 1.0000x reference)
//
#include <hip/hip_runtime.h>

typedef unsigned short ushort_t;
typedef __attribute__((ext_vector_type(8))) _Float16 half8;
typedef __attribute__((ext_vector_type(4))) _Float16 half4;
typedef __attribute__((ext_vector_type(8))) __bf16 bf16x8;
typedef __attribute__((ext_vector_type(4))) float f32x4;

#define MARGIN 1e-4f

__device__ __forceinline__ ushort_t f2bf(float f){
  union { float f; unsigned int i; } v; v.f = f;
  unsigned int x = v.i;
  unsigned int r = (x + 0x7fffu + ((x >> 16) & 1u)) >> 16;
  return (ushort_t)r;
}

// ---------------------------------------------------------------------------
// prep: We (fp32,1048576) -> bf16 ws; Wr1 (fp32,65536) -> f16 hi + scaled lo.
// ---------------------------------------------------------------------------
__global__ __launch_bounds__(256) void k_prep(const float* __restrict__ We,
    const float* __restrict__ Wr1, ushort_t* __restrict__ Web,
    _Float16* __restrict__ W1h, _Float16* __restrict__ W1l)
{
  int idx = blockIdx.x*256 + threadIdx.x;
  if (idx < 1048576) Web[idx] = f2bf(We[idx]);
  if (idx < 65536){
    float v = Wr1[idx];
    _Float16 h = (_Float16)v;
    float rem = (v - (float)h) * 4096.f;
    W1h[idx] = h;
    W1l[idx] = (_Float16)rem;
  }
}

// ---------------------------------------------------------------------------
// Fused GEMM1 (f16 3-term split MFMA, fp32-grade) + router logits (fp32 VALU)
// + top2 + softmax + near-tie flagging. 64 tokens/block.
// ---------------------------------------------------------------------------
__global__ __launch_bounds__(256) void r1r2_fused(const float* __restrict__ x,
    const _Float16* __restrict__ W1h, const _Float16* __restrict__ W1l,
    const float* __restrict__ br1, const float* __restrict__ Wr2,
    const float* __restrict__ br2,
    int* __restrict__ pid, float2* __restrict__ pAB,
    int* __restrict__ fixCnt, int* __restrict__ fixTok)
{
  __shared__ __align__(16) char smem[55296];
  _Float16* Ah = (_Float16*)smem;            // 64 x 72
  _Float16* Al = (_Float16*)(smem +  9216);  // 64 x 72
  _Float16* Bs = (_Float16*)(smem + 18432);  // 256 x 72
  const int tid = threadIdx.x;
  const int wave = tid>>6, lane = tid&63, q = lane>>4, col = lane&15;
  const int tok0 = blockIdx.x * 64;

  f32x4 accH[4][4], accC[4][4];
  #pragma unroll
  for (int i=0;i<4;i++)
    #pragma unroll
    for (int j=0;j<4;j++){ accH[i][j] = f32x4{0.f,0.f,0.f,0.f}; accC[i][j] = f32x4{0.f,0.f,0.f,0.f}; }

  for (int kc = 0; kc < 4; ++kc){
    const int kb = kc*64;
    __syncthreads();
    // stage A (x fp32 -> f16 hi + scaled lo)
    #pragma unroll
    for (int j=0;j<4;j++){
      int idx = j*256 + tid, row = idx>>4, c4 = idx&15;
      f32x4 xv = *(const f32x4*)&x[(tok0+row)*256 + kb + c4*4];
      half4 hv, lv;
      #pragma unroll
      for (int m=0;m<4;m++){
        float v = xv[m];
        _Float16 h = (_Float16)v;
        hv[m] = h;
        lv[m] = (_Float16)((v - (float)h) * 4096.f);
      }
      *(half4*)&Ah[row*72 + c4*4] = hv;
      *(half4*)&Al[row*72 + c4*4] = lv;
    }
    // stage B = W1h chunk
    #pragma unroll
    for (int j=0;j<8;j++){
      int idx = j*256 + tid, row = idx>>3, c8 = idx&7;
      *(uint4*)&Bs[row*72 + c8*8] = *(const uint4*)&W1h[row*256 + kb + c8*8];
    }
    __syncthreads();
    #pragma unroll
    for (int kk=0;kk<2;kk++){
      half8 a_h[4], a_l[4], b[4];
      #pragma unroll
      for (int rf=0;rf<4;rf++){
        a_h[rf] = *(const half8*)&Ah[(rf*16+col)*72 + kk*32 + q*8];
        a_l[rf] = *(const half8*)&Al[(rf*16+col)*72 + kk*32 + q*8];
      }
      #pragma unroll
      for (int cf=0;cf<4;cf++) b[cf] = *(const half8*)&Bs[(wave*64+cf*16+col)*72 + kk*32 + q*8];
      #pragma unroll
      for (int rf=0;rf<4;rf++)
        #pragma unroll
        for (int cf=0;cf<4;cf++){
          accH[rf][cf] = __builtin_amdgcn_mfma_f32_16x16x32_f16(a_h[rf], b[cf], accH[rf][cf], 0,0,0);
          accC[rf][cf] = __builtin_amdgcn_mfma_f32_16x16x32_f16(a_l[rf], b[cf], accC[rf][cf], 0,0,0);
        }
    }
    __syncthreads();
    // stage B = W1l chunk (scaled lo)
    #pragma unroll
    for (int j=0;j<8;j++){
      int idx = j*256 + tid, row = idx>>3, c8 = idx&7;
      *(uint4*)&Bs[row*72 + c8*8] = *(const uint4*)&W1l[row*256 + kb + c8*8];
    }
    __syncthreads();
    #pragma unroll
    for (int kk=0;kk<2;kk++){
      half8 a_h[4], b[4];
      #pragma unroll
      for (int rf=0;rf<4;rf++) a_h[rf] = *(const half8*)&Ah[(rf*16+col)*72 + kk*32 + q*8];
      #pragma unroll
      for (int cf=0;cf<4;cf++) b[cf] = *(const half8*)&Bs[(wave*64+cf*16+col)*72 + kk*32 + q*8];
      #pragma unroll
      for (int rf=0;rf<4;rf++)
        #pragma unroll
        for (int cf=0;cf<4;cf++)
          accC[rf][cf] = __builtin_amdgcn_mfma_f32_16x16x32_f16(a_h[rf], b[cf], accC[rf][cf], 0,0,0);
    }
  }

  // combine hi + 2^-12 * cross, add bias, leaky  (accH becomes h, fp32)
  {
    float br1v[4];
    #pragma unroll
    for (int cf=0;cf<4;cf++) br1v[cf] = br1[wave*64 + cf*16 + col];
    #pragma unroll
    for (int rf=0;rf<4;rf++)
      #pragma unroll
      for (int cf=0;cf<4;cf++)
        #pragma unroll
        for (int r=0;r<4;r++){
          float p = accH[rf][cf][r] + 0.000244140625f*accC[rf][cf][r] + br1v[cf];
          accH[rf][cf][r] = p > 0.f ? p : 0.01f*p;
        }
  }

  __syncthreads();
  // reuse LDS: w2t[256][16], lp[4][64][16]
  float* w2t = (float*)smem;
  float* lp  = (float*)(smem + 16384);
  {
    int o = tid;
    #pragma unroll
    for (int e=0;e<16;e++) w2t[o*16 + e] = Wr2[e*256 + o];
  }
  __syncthreads();

  // logit partials: per lane 16 rows x 4 o's; butterfly over 16 cols
  #pragma unroll
  for (int rf=0;rf<4;rf++)
    #pragma unroll
    for (int r=0;r<4;r++){
      const int row = rf*16 + q*4 + r;
      float c[16];
      #pragma unroll
      for (int e=0;e<16;e++) c[e] = 0.f;
      #pragma unroll
      for (int cf=0;cf<4;cf++){
        const int o = wave*64 + cf*16 + col;
        float hval = accH[rf][cf][r];
        const f32x4* wp = (const f32x4*)&w2t[o*16];
        #pragma unroll
        for (int jj=0;jj<4;jj++){
          f32x4 w4 = wp[jj];
          c[jj*4+0] += hval*w4[0];
          c[jj*4+1] += hval*w4[1];
          c[jj*4+2] += hval*w4[2];
          c[jj*4+3] += hval*w4[3];
        }
      }
      #pragma unroll
      for (int m=1;m<16;m<<=1)
        #pragma unroll
        for (int e=0;e<16;e++) c[e] += __shfl_xor(c[e], m, 16);
      if (col == 0){
        #pragma unroll
        for (int e=0;e<16;e++) lp[(wave*64 + row)*16 + e] = c[e];
      }
    }
  __syncthreads();

  if (tid < 64){
    const int tok = tok0 + tid;
    float v[16];
    #pragma unroll
    for (int e=0;e<16;e++)
      v[e] = lp[(0*64+tid)*16+e] + lp[(1*64+tid)*16+e] + lp[(2*64+tid)*16+e]
           + lp[(3*64+tid)*16+e] + br2[e];
    float best=-3.4e38f, sec=-3.4e38f, thr=-3.4e38f; int b1=0, b2=0;
    #pragma unroll
    for (int e=0;e<16;e++){
      float val = v[e];
      if (val > best){ thr=sec; sec=best; b2=b1; best=val; b1=e; }
      else if (val > sec){ thr=sec; sec=val; b2=e; }
      else if (val > thr){ thr=val; }
    }
    float ex = __expf(sec - best);  // replaced below by precise expf
    ex = expf(sec - best);
    float s = 1.f + ex;
    float p1 = 1.f/s, p2 = ex/s;
    int eA = b1 < b2 ? b1 : b2;
    int eB = b1 < b2 ? b2 : b1;
    float pA = b1 < b2 ? p1 : p2;
    float pB = b1 < b2 ? p2 : p1;
    pid[tok] = eA*16 + eB;
    pAB[tok] = make_float2(pA, pB);
    if (sec - thr < MARGIN){
      int slot = atomicAdd(fixCnt, 1);
      fixTok[slot] = tok;
    }
  }
}

// ---------------------------------------------------------------------------
// fp64 exact router recompute for near-tie tokens. 1 wave per token.
// ---------------------------------------------------------------------------
__global__ __launch_bounds__(64) void k_fixup(const float* __restrict__ x,
    const float* __restrict__ Wr1, const float* __restrict__ br1,
    const float* __restrict__ Wr2, const float* __restrict__ br2,
    const int* __restrict__ fixCnt, const int* __restrict__ fixTok,
    int* __restrict__ pid, float2* __restrict__ pAB)
{
  __shared__ float  xs[256];
  __shared__ double hs[256];
  __shared__ double lg[16];
  const int l = threadIdx.x;
  const int n = *fixCnt;
  for (int it = blockIdx.x; it < n; it += gridDim.x){
    const int tok = fixTok[it];
    __syncthreads();
    #pragma unroll
    for (int j=0;j<4;j++) xs[j*64+l] = x[tok*256 + j*64 + l];
    __syncthreads();
    #pragma unroll
    for (int jo=0;jo<4;jo++){
      int o = jo*64 + l;
      double acc = 0.0;
      for (int k4=0;k4<64;k4++){
        f32x4 w = *(const f32x4*)&Wr1[o*256 + k4*4];
        f32x4 xv = *(const f32x4*)&xs[k4*4];
        acc += (double)xv[0]*(double)w[0];
        acc += (double)xv[1]*(double)w[1];
        acc += (double)xv[2]*(double)w[2];
        acc += (double)xv[3]*(double)w[3];
      }
      acc += (double)br1[o];
      hs[o] = acc > 0.0 ? acc : 0.01*acc;
    }
    __syncthreads();
    if (l < 16){
      double a = 0.0;
      for (int k4=0;k4<64;k4++){
        f32x4 w = *(const f32x4*)&Wr2[l*256 + k4*4];
        a += hs[k4*4+0]*(double)w[0];
        a += hs[k4*4+1]*(double)w[1];
        a += hs[k4*4+2]*(double)w[2];
        a += hs[k4*4+3]*(double)w[3];
      }
      lg[l] = a + (double)br2[l];
    }
    __syncthreads();
    if (l == 0){
      double best=-1e300, sec=-1e300; int b1=0, b2=0;
      #pragma unroll
      for (int e=0;e<16;e++){
        double val = lg[e];
        if (val > best){ sec=best; b2=b1; best=val; b1=e; }
        else if (val > sec){ sec=val; b2=e; }
      }
      double ex = exp(sec - best);
      double s = 1.0 + ex;
      double p1 = 1.0/s, p2 = ex/s;
      int eA = b1 < b2 ? b1 : b2;
      int eB = b1 < b2 ? b2 : b1;
      float pA = (float)(b1 < b2 ? p1 : p2);
      float pB = (float)(b1 < b2 ? p2 : p1);
      pid[tok] = eA*16 + eB;
      pAB[tok] = make_float2(pA, pB);
    }
  }
}

__global__ __launch_bounds__(256) void k_hist(const int* __restrict__ pid, int* __restrict__ cnt)
{
  int b = blockIdx.x*256 + threadIdx.x;
  atomicAdd(&cnt[pid[b]], 1);
}

__global__ __launch_bounds__(256) void k_scan(int* __restrict__ cnt, int* __restrict__ cur,
    int* __restrict__ off, int* __restrict__ tileOff)
{
  __shared__ int sc[256];
  const int tid = threadIdx.x;
  int c = cnt[tid];
  sc[tid] = c; __syncthreads();
  for (int s=1;s<256;s<<=1){ int v = (tid>=s)? sc[tid-s]:0; __syncthreads(); sc[tid]+=v; __syncthreads(); }
  int inc = sc[tid];
  off[tid] = inc - c;
  cur[tid] = inc - c;
  if (tid==255) off[256] = inc;
  int tc = (c+63)>>6;
  __syncthreads();
  sc[tid] = tc; __syncthreads();
  for (int s=1;s<256;s<<=1){ int v = (tid>=s)? sc[tid-s]:0; __syncthreads(); sc[tid]+=v; __syncthreads(); }
  tileOff[tid] = sc[tid] - tc;
  if (tid==255) tileOff[256] = sc[tid];
}

__global__ __launch_bounds__(256) void k_scatter(const int* __restrict__ pid,
    int* __restrict__ cur, int* __restrict__ sortedTok)
{
  int b = blockIdx.x*256 + threadIdx.x;
  int p = pid[b];
  int slot = atomicAdd(&cur[p], 1);
  sortedTok[slot] = b;
}

// ---------------------------------------------------------------------------
// Expert pair GEMM: bf16 MFMA, probs folded into A staging, fp32 output via
// 2-phase LDS transpose for coalesced float4 stores.
// ---------------------------------------------------------------------------
__global__ __launch_bounds__(256) void k_expert(const float* __restrict__ x,
    const ushort_t* __restrict__ Web, const float* __restrict__ be,
    const int* __restrict__ off, const int* __restrict__ tileOff,
    const int* __restrict__ sortedTok, const float2* __restrict__ pAB,
    float* __restrict__ out)
{
  const int totTiles = tileOff[256];
  const int bid = blockIdx.x;
  if (bid >= totTiles) return;
  __shared__ __align__(16) char smem[46080];
  ushort_t* As = (ushort_t*)smem;             // 64 x 72 bf16
  ushort_t* Bs = (ushort_t*)(smem + 9216);    // 256 x 72 bf16
  __shared__ int toks[64];
  __shared__ float pAs[64], pBs[64];
  __shared__ int sh_p;
  const int tid = threadIdx.x;
  if (tid == 0){
    int lo=0, hi=255;
    while (lo < hi){ int mid=(lo+hi+1)>>1; if (tileOff[mid] <= bid) lo=mid; else hi=mid-1; }
    sh_p = lo;
  }
  __syncthreads();
  const int p = sh_p;
  const int tstart = off[p] + (bid - tileOff[p])*64;
  const int nt = min(64, off[p+1] - tstart);
  if (tid < 64){
    if (tid < nt){
      int t = sortedTok[tstart + tid];
      toks[tid] = t;
      float2 ab = pAB[t];
      pAs[tid] = ab.x; pBs[tid] = ab.y;
    } else { toks[tid] = -1; pAs[tid]=0.f; pBs[tid]=0.f; }
  }
  const int wave = tid>>6, lane = tid&63, q = lane>>4, col = lane&15;
  const int eA = p >> 4, eB = p & 15;
  f32x4 acc[4][4];
  #pragma unroll
  for (int i=0;i<4;i++)
    #pragma unroll
    for (int j=0;j<4;j++) acc[i][j] = f32x4{0.f,0.f,0.f,0.f};

  for (int pass=0; pass<2; ++pass){
    const int e = pass ? eB : eA;
    const ushort_t* W = Web + e*65536;
    for (int kc=0; kc<4; ++kc){
      const int kb = kc*64;
      __syncthreads();
      // A: gather x fp32, scale by prob, convert bf16
      #pragma unroll
      for (int j=0;j<4;j++){
        int idx = j*256 + tid, row = idx>>4, c4 = idx&15;
        int t = toks[row];
        ushort4 val = make_ushort4(0,0,0,0);
        if (t >= 0){
          float ps = pass ? pBs[row] : pAs[row];
          f32x4 xv = *(const f32x4*)&x[t*256 + kb + c4*4];
          val.x = f2bf(xv[0]*ps);
          val.y = f2bf(xv[1]*ps);
          val.z = f2bf(xv[2]*ps);
          val.w = f2bf(xv[3]*ps);
        }
        *(ushort4*)&As[row*72 + c4*4] = val;
      }
      #pragma unroll
      for (int j=0;j<8;j++){
        int idx = j*256 + tid, row = idx>>3, c8 = idx&7;
        *(uint4*)&Bs[row*72 + c8*8] = *(const uint4*)&W[row*256 + kb + c8*8];
      }
      __syncthreads();
      #pragma unroll
      for (int kk=0;kk<2;kk++){
        bf16x8 a[4], b[4];
        #pragma unroll
        for (int rf=0;rf<4;rf++) a[rf] = *(const bf16x8*)&As[(rf*16+col)*72 + kk*32 + q*8];
        #pragma unroll
        for (int cf=0;cf<4;cf++) b[cf] = *(const bf16x8*)&Bs[(wave*64+cf*16+col)*72 + kk*32 + q*8];
        #pragma unroll
        for (int rf=0;rf<4;rf++)
          #pragma unroll
          for (int cf=0;cf<4;cf++)
            acc[rf][cf] = __builtin_amdgcn_mfma_f32_16x16x32_bf16(a[rf], b[cf], acc[rf][cf], 0,0,0);
      }
    }
  }

  // epilogue: 2-phase fp32 transpose through LDS (reuse staging region)
  float* obuf = (float*)smem;   // 32 x 264 fp32 = 33792 B
  #pragma unroll
  for (int ph=0; ph<2; ++ph){
    __syncthreads();
    #pragma unroll
    for (int cf=0;cf<4;cf++){
      int o = wave*64 + cf*16 + col;
      float bA = be[eA*256 + o];
      float bB = be[eB*256 + o];
      #pragma unroll
      for (int rr=0;rr<2;rr++){
        int rf = ph*2 + rr;
        #pragma unroll
        for (int r=0;r<4;r++){
          int row = rf*16 + q*4 + r;
          float v = acc[rf][cf][r] + pAs[row]*bA + pBs[row]*bB;
          v = v > 0.f ? v : 0.01f*v;
          obuf[(row - ph*32)*264 + o] = v;
        }
      }
    }
    __syncthreads();
    #pragma unroll
    for (int j=0;j<8;j++){
      int idx = j*256 + tid;
      int lrow = idx>>6, c4 = idx&63;
      int row = ph*32 + lrow;
      int t = toks[row];
      if (t >= 0)
        *(f32x4*)&out[t*256 + c4*4] = *(const f32x4*)&obuf[lrow*264 + c4*4];
    }
  }
}

// ---------------------------------------------------------------------------
extern "C" void kernel_launch(void* const* d_in, const int* in_sizes, int n_in,
                              void* d_out, int out_size, void* d_ws, size_t ws_size,
                              hipStream_t stream)
{
  const float* x   = (const float*)d_in[0];
  const float* Wr1 = (const float*)d_in[1];
  const float* br1 = (const float*)d_in[2];
  const float* Wr2 = (const float*)d_in[3];
  const float* br2 = (const float*)d_in[4];
  const float* We  = (const float*)d_in[5];
  const float* be  = (const float*)d_in[6];
  float* out = (float*)d_out;

  char* ws = (char*)d_ws;
  ushort_t* Web      = (ushort_t*)ws;                 // 2 MiB
  _Float16* W1h      = (_Float16*)(ws + 2097152);     // 128 KiB
  _Float16* W1l      = (_Float16*)(ws + 2228224);     // 128 KiB
  int*      pid      = (int*)(ws + 2359296);          // 256 KiB
  float2*   pAB      = (float2*)(ws + 2621440);       // 512 KiB
  int*      sortedTok= (int*)(ws + 3145728);          // 256 KiB
  int*      fixTok   = (int*)(ws + 3407872);          // 256 KiB
  int*      cnt      = (int*)(ws + 3670016);          // 256 ints
  int*      fixCnt   = cnt + 256;                     // 1 int
  int*      cur      = cnt + 272;                     // 256 ints
  int*      off      = cnt + 528;                     // 257 ints
  int*      tileOff  = cnt + 785;                     // 257 ints

  hipMemsetAsync(cnt, 0, 257*sizeof(int), stream);
  k_prep    <<<4096, 256, 0, stream>>>(We, Wr1, Web, W1h, W1l);
  r1r2_fused<<<1024, 256, 0, stream>>>(x, W1h, W1l, br1, Wr2, br2, pid, pAB, fixCnt, fixTok);
  k_fixup   <<<512,   64, 0, stream>>>(x, Wr1, br1, Wr2, br2, fixCnt, fixTok, pid, pAB);
  k_hist    <<<256,  256, 0, stream>>>(pid, cnt);
  k_scan    <<<1,    256, 0, stream>>>(cnt, cur, off, tileOff);
  k_scatter <<<256,  256, 0, stream>>>(pid, cur, sortedTok);
  k_expert  <<<1160, 256, 0, stream>>>(x, Web, be, off, tileOff, sortedTok, pAB, out);
}

// Round 4
// 417.888 us; speedup vs baseline: 1.1198x; 1.1198x over previous
//
#include <hip/hip_runtime.h>

typedef unsigned short ushort_t;
typedef __attribute__((ext_vector_type(8))) __bf16 bf16x8;
typedef __attribute__((ext_vector_type(4))) float f32x4;

#define MARGIN 1.5e-3f

__device__ __forceinline__ float bf2f(ushort_t u){
  union { unsigned int i; float f; } v; v.i = ((unsigned int)u) << 16; return v.f;
}
__device__ __forceinline__ ushort_t f2bf(float f){
  union { float f; unsigned int i; } v; v.f = f;
  unsigned int x = v.i;
  return (ushort_t)((x + 0x7fffu + ((x >> 16) & 1u)) >> 16);
}
// async global->LDS, 16B per lane; LDS dest is wave-uniform base + lane*16
__device__ __forceinline__ void async_load16(const void* g, void* l){
  __builtin_amdgcn_global_load_lds((const __attribute__((address_space(1))) void*)g,
                                   (__attribute__((address_space(3))) void*)l, 16, 0, 0);
}

// ---------------------------------------------------------------------------
// prep: We -> bf16; Wr1 -> bf16; Wr2 -> bf16 hi + bf16 residual (lo).
// ---------------------------------------------------------------------------
__global__ __launch_bounds__(256) void k_prep(const float* __restrict__ We,
    const float* __restrict__ Wr1, const float* __restrict__ Wr2,
    ushort_t* __restrict__ Web, ushort_t* __restrict__ W1b,
    ushort_t* __restrict__ W2h, ushort_t* __restrict__ W2l)
{
  int idx = blockIdx.x*256 + threadIdx.x;
  if (idx < 1048576) Web[idx] = f2bf(We[idx]);
  if (idx < 65536)   W1b[idx] = f2bf(Wr1[idx]);
  if (idx < 4096){
    float w = Wr2[idx];
    ushort_t wh = f2bf(w);
    W2h[idx] = wh;
    W2l[idx] = f2bf(w - bf2f(wh));   // residual, captures next ~8 bits
  }
}

// ---------------------------------------------------------------------------
// Fused GEMM1 (bf16 MFMA) + logits MFMA (bf16 h x split-bf16 Wr2) + top2 +
// softmax + near-tie flagging. 64 tokens/block.
// LDS: As 64x72 bf16 (9216) | Bs 256x128B swizzled (32768) -> reused as
//      hB 64x264 bf16 (33792); lg 64x17 f32 (4352) at offset 41984.
// ---------------------------------------------------------------------------
__global__ __launch_bounds__(256) void r1r2_fused(const float* __restrict__ x,
    const ushort_t* __restrict__ W1b, const float* __restrict__ br1,
    const ushort_t* __restrict__ W2h, const ushort_t* __restrict__ W2l,
    const float* __restrict__ br2,
    int* __restrict__ pid, float2* __restrict__ pAB,
    int* __restrict__ fixCnt, int* __restrict__ fixTok)
{
  __shared__ __align__(16) char smem[46336];
  ushort_t* As = (ushort_t*)smem;              // 64 x 72
  char*     Bs = smem + 9216;                  // 256 rows x 128B, XOR-swizzled
  ushort_t* hB = (ushort_t*)smem;              // 64 x 264 (reuse after K-loop)
  float*    lg = (float*)(smem + 41984);       // 64 x 17
  const int tid = threadIdx.x;
  const int wave = tid>>6, lane = tid&63, q = lane>>4, col = lane&15;
  const int tok0 = blockIdx.x*64;

  f32x4 acc[4][4];
  #pragma unroll
  for (int i=0;i<4;i++)
    #pragma unroll
    for (int j=0;j<4;j++) acc[i][j] = f32x4{0.f,0.f,0.f,0.f};

  for (int kc = 0; kc < 4; ++kc){
    const int kb = kc*64;
    __syncthreads();
    // B: 32KB via global_load_lds; wave stages rows [wave*64, wave*64+64)
    #pragma unroll
    for (int i=0;i<8;i++){
      int r0 = wave*64 + i*8;
      int grow = r0 + (lane>>3);
      int kc8 = (lane&7) ^ (grow&7);
      async_load16(W1b + grow*256 + kb + kc8*8, Bs + r0*128);
    }
    // A: x fp32 -> bf16
    #pragma unroll
    for (int j=0;j<2;j++){
      int idx = j*256 + tid, row = idx>>3, c8 = idx&7;
      f32x4 v0 = *(const f32x4*)&x[(tok0+row)*256 + kb + c8*8];
      f32x4 v1 = *(const f32x4*)&x[(tok0+row)*256 + kb + c8*8 + 4];
      union { uint4 u; ushort_t s[8]; } pk;
      pk.s[0]=f2bf(v0[0]); pk.s[1]=f2bf(v0[1]); pk.s[2]=f2bf(v0[2]); pk.s[3]=f2bf(v0[3]);
      pk.s[4]=f2bf(v1[0]); pk.s[5]=f2bf(v1[1]); pk.s[6]=f2bf(v1[2]); pk.s[7]=f2bf(v1[3]);
      *(uint4*)&As[row*72 + c8*8] = pk.u;
    }
    __syncthreads();
    #pragma unroll
    for (int kk=0;kk<2;kk++){
      bf16x8 a[4], b[4];
      #pragma unroll
      for (int rf=0;rf<4;rf++) a[rf] = *(const bf16x8*)&As[(rf*16+col)*72 + kk*32 + q*8];
      #pragma unroll
      for (int cf=0;cf<4;cf++){
        int n = wave*64 + cf*16 + col;
        b[cf] = *(const bf16x8*)(Bs + n*128 + (((kk*4+q) ^ (n&7))*16));
      }
      #pragma unroll
      for (int rf=0;rf<4;rf++)
        #pragma unroll
        for (int cf=0;cf<4;cf++)
          acc[rf][cf] = __builtin_amdgcn_mfma_f32_16x16x32_bf16(a[rf], b[cf], acc[rf][cf], 0,0,0);
    }
  }
  __syncthreads();
  // h = leaky(acc + br1) -> bf16 into hB
  {
    float br1v[4];
    #pragma unroll
    for (int cf=0;cf<4;cf++) br1v[cf] = br1[wave*64 + cf*16 + col];
    #pragma unroll
    for (int rf=0;rf<4;rf++)
      #pragma unroll
      for (int cf=0;cf<4;cf++){
        int o = wave*64 + cf*16 + col;
        #pragma unroll
        for (int r=0;r<4;r++){
          int row = rf*16 + q*4 + r;
          float p = acc[rf][cf][r] + br1v[cf];
          p = p > 0.f ? p : 0.01f*p;
          hB[row*264 + o] = f2bf(p);
        }
      }
  }
  __syncthreads();
  // logits[64x16] = h @ Wr2^T via MFMA; wave handles its 16-token m-tile
  {
    f32x4 acc2 = f32x4{0.f,0.f,0.f,0.f};
    #pragma unroll
    for (int c2=0;c2<8;c2++){
      bf16x8 a2 = *(const bf16x8*)&hB[(wave*16+col)*264 + c2*32 + q*8];
      bf16x8 bh = *(const bf16x8*)&W2h[col*256 + c2*32 + q*8];
      bf16x8 bl = *(const bf16x8*)&W2l[col*256 + c2*32 + q*8];
      acc2 = __builtin_amdgcn_mfma_f32_16x16x32_bf16(a2, bh, acc2, 0,0,0);
      acc2 = __builtin_amdgcn_mfma_f32_16x16x32_bf16(a2, bl, acc2, 0,0,0);
    }
    #pragma unroll
    for (int r=0;r<4;r++) lg[(wave*16 + q*4 + r)*17 + col] = acc2[r];
  }
  __syncthreads();
  if (tid < 64){
    const int tok = tok0 + tid;
    float v[16];
    #pragma unroll
    for (int e=0;e<16;e++) v[e] = lg[tid*17 + e] + br2[e];
    float best=-3.4e38f, sec=-3.4e38f, thr=-3.4e38f; int b1=0, b2=0;
    #pragma unroll
    for (int e=0;e<16;e++){
      float val = v[e];
      if (val > best){ thr=sec; sec=best; b2=b1; best=val; b1=e; }
      else if (val > sec){ thr=sec; sec=val; b2=e; }
      else if (val > thr){ thr=val; }
    }
    float ex = expf(sec - best);
    float s = 1.f + ex;
    float p1 = 1.f/s, p2 = ex/s;
    int eA = b1 < b2 ? b1 : b2;
    int eB = b1 < b2 ? b2 : b1;
    float pA = b1 < b2 ? p1 : p2;
    float pB = b1 < b2 ? p2 : p1;
    pid[tok] = eA*16 + eB;
    pAB[tok] = make_float2(pA, pB);
    if (sec - thr < MARGIN){
      int slot = atomicAdd(fixCnt, 1);
      fixTok[slot] = tok;
    }
  }
}

// ---------------------------------------------------------------------------
// fp64 exact router recompute for near-tie tokens. One 256-thread block/token.
// ---------------------------------------------------------------------------
__global__ __launch_bounds__(256) void k_fixup(const float* __restrict__ x,
    const float* __restrict__ Wr1, const float* __restrict__ br1,
    const float* __restrict__ Wr2, const float* __restrict__ br2,
    const int* __restrict__ fixCnt, const int* __restrict__ fixTok,
    int* __restrict__ pid, float2* __restrict__ pAB)
{
  __shared__ float  xs[256];
  __shared__ double hs[256];
  __shared__ double lgs[16];
  const int tid = threadIdx.x;
  const int n = *fixCnt;
  for (int it = blockIdx.x; it < n; it += gridDim.x){
    const int tok = fixTok[it];
    __syncthreads();
    xs[tid] = x[tok*256 + tid];
    __syncthreads();
    {
      const int o = tid;
      double a0=0,a1=0,a2=0,a3=0;
      #pragma unroll 8
      for (int k=0;k<64;k++){
        f32x4 w  = *(const f32x4*)&Wr1[o*256 + k*4];
        f32x4 xv = *(const f32x4*)&xs[k*4];
        a0 += (double)xv[0]*(double)w[0];
        a1 += (double)xv[1]*(double)w[1];
        a2 += (double)xv[2]*(double)w[2];
        a3 += (double)xv[3]*(double)w[3];
      }
      double acc = ((a0+a1)+(a2+a3)) + (double)br1[o];
      hs[o] = acc > 0.0 ? acc : 0.01*acc;
    }
    __syncthreads();
    if (tid < 16){
      double a0=0,a1=0,a2=0,a3=0;
      #pragma unroll 8
      for (int k=0;k<64;k++){
        f32x4 w = *(const f32x4*)&Wr2[tid*256 + k*4];
        a0 += hs[k*4+0]*(double)w[0];
        a1 += hs[k*4+1]*(double)w[1];
        a2 += hs[k*4+2]*(double)w[2];
        a3 += hs[k*4+3]*(double)w[3];
      }
      lgs[tid] = ((a0+a1)+(a2+a3)) + (double)br2[tid];
    }
    __syncthreads();
    if (tid == 0){
      double best=-1e300, sec=-1e300; int b1=0, b2=0;
      #pragma unroll
      for (int e=0;e<16;e++){
        double val = lgs[e];
        if (val > best){ sec=best; b2=b1; best=val; b1=e; }
        else if (val > sec){ sec=val; b2=e; }
      }
      double ex = exp(sec - best);
      double s = 1.0 + ex;
      double p1 = 1.0/s, p2 = ex/s;
      int eA = b1 < b2 ? b1 : b2;
      int eB = b1 < b2 ? b2 : b1;
      float pA = (float)(b1 < b2 ? p1 : p2);
      float pB = (float)(b1 < b2 ? p2 : p1);
      pid[tok] = eA*16 + eB;
      pAB[tok] = make_float2(pA, pB);
    }
  }
}

__global__ __launch_bounds__(256) void k_hist(const int* __restrict__ pid, int* __restrict__ cnt)
{
  __shared__ int hc[256];
  const int tid = threadIdx.x;
  hc[tid] = 0; __syncthreads();
  atomicAdd(&hc[pid[blockIdx.x*256 + tid]], 1);
  __syncthreads();
  if (hc[tid]) atomicAdd(&cnt[tid], hc[tid]);
}

__global__ __launch_bounds__(256) void k_scan(int* __restrict__ cnt, int* __restrict__ cur,
    int* __restrict__ off, int* __restrict__ tileOff)
{
  __shared__ int sc[256];
  const int tid = threadIdx.x;
  int c = cnt[tid];
  sc[tid] = c; __syncthreads();
  for (int s=1;s<256;s<<=1){ int v = (tid>=s)? sc[tid-s]:0; __syncthreads(); sc[tid]+=v; __syncthreads(); }
  int inc = sc[tid];
  off[tid] = inc - c;
  cur[tid] = inc - c;
  if (tid==255) off[256] = inc;
  int tc = (c+63)>>6;
  __syncthreads();
  sc[tid] = tc; __syncthreads();
  for (int s=1;s<256;s<<=1){ int v = (tid>=s)? sc[tid-s]:0; __syncthreads(); sc[tid]+=v; __syncthreads(); }
  tileOff[tid] = sc[tid] - tc;
  if (tid==255) tileOff[256] = sc[tid];
}

__global__ __launch_bounds__(256) void k_scatter(const int* __restrict__ pid,
    int* __restrict__ cur, int* __restrict__ sortedTok)
{
  int b = blockIdx.x*256 + threadIdx.x;
  int p = pid[b];
  int slot = atomicAdd(&cur[p], 1);
  sortedTok[slot] = b;
}

// ---------------------------------------------------------------------------
// Expert pair GEMM: bf16 MFMA, probs folded into A staging, B tiles via
// global_load_lds (XOR-swizzled), fp32 output via 2-phase LDS transpose.
// LDS: As 64x72 (9216) | Bs 256x128B swizzled (32768); obuf reuses base.
// ---------------------------------------------------------------------------
__global__ __launch_bounds__(256) void k_expert(const float* __restrict__ x,
    const ushort_t* __restrict__ Web, const float* __restrict__ be,
    const int* __restrict__ off, const int* __restrict__ tileOff,
    const int* __restrict__ sortedTok, const float2* __restrict__ pAB,
    float* __restrict__ out)
{
  const int totTiles = tileOff[256];
  const int bid = blockIdx.x;
  if (bid >= totTiles) return;
  __shared__ __align__(16) char smem[41984];
  ushort_t* As = (ushort_t*)smem;          // 64 x 72
  char*     Bs = smem + 9216;              // 256 rows x 128B, swizzled
  __shared__ int toks[64];
  __shared__ float pAs[64], pBs[64];
  __shared__ int sh_p;
  const int tid = threadIdx.x;
  if (tid == 0){
    int lo=0, hi=255;
    while (lo < hi){ int mid=(lo+hi+1)>>1; if (tileOff[mid] <= bid) lo=mid; else hi=mid-1; }
    sh_p = lo;
  }
  __syncthreads();
  const int p = sh_p;
  const int tstart = off[p] + (bid - tileOff[p])*64;
  const int nt = min(64, off[p+1] - tstart);
  if (tid < 64){
    if (tid < nt){
      int t = sortedTok[tstart + tid];
      toks[tid] = t;
      float2 ab = pAB[t];
      pAs[tid] = ab.x; pBs[tid] = ab.y;
    } else { toks[tid] = -1; pAs[tid]=0.f; pBs[tid]=0.f; }
  }
  const int wave = tid>>6, lane = tid&63, q = lane>>4, col = lane&15;
  const int eA = p >> 4, eB = p & 15;
  f32x4 acc[4][4];
  #pragma unroll
  for (int i=0;i<4;i++)
    #pragma unroll
    for (int j=0;j<4;j++) acc[i][j] = f32x4{0.f,0.f,0.f,0.f};

  for (int pass=0; pass<2; ++pass){
    const ushort_t* W = Web + (pass ? eB : eA)*65536;
    for (int kc=0; kc<4; ++kc){
      const int kb = kc*64;
      __syncthreads();
      #pragma unroll
      for (int i=0;i<8;i++){
        int r0 = wave*64 + i*8;
        int grow = r0 + (lane>>3);
        int kc8 = (lane&7) ^ (grow&7);
        async_load16(W + grow*256 + kb + kc8*8, Bs + r0*128);
      }
      #pragma unroll
      for (int j=0;j<2;j++){
        int idx = j*256 + tid, row = idx>>3, c8 = idx&7;
        int t = toks[row];
        uint4 val = make_uint4(0u,0u,0u,0u);
        if (t >= 0){
          float ps = pass ? pBs[row] : pAs[row];
          f32x4 v0 = *(const f32x4*)&x[t*256 + kb + c8*8];
          f32x4 v1 = *(const f32x4*)&x[t*256 + kb + c8*8 + 4];
          union { uint4 u; ushort_t s[8]; } pk;
          pk.s[0]=f2bf(v0[0]*ps); pk.s[1]=f2bf(v0[1]*ps); pk.s[2]=f2bf(v0[2]*ps); pk.s[3]=f2bf(v0[3]*ps);
          pk.s[4]=f2bf(v1[0]*ps); pk.s[5]=f2bf(v1[1]*ps); pk.s[6]=f2bf(v1[2]*ps); pk.s[7]=f2bf(v1[3]*ps);
          val = pk.u;
        }
        *(uint4*)&As[row*72 + c8*8] = val;
      }
      __syncthreads();
      #pragma unroll
      for (int kk=0;kk<2;kk++){
        bf16x8 a[4], b[4];
        #pragma unroll
        for (int rf=0;rf<4;rf++) a[rf] = *(const bf16x8*)&As[(rf*16+col)*72 + kk*32 + q*8];
        #pragma unroll
        for (int cf=0;cf<4;cf++){
          int n = wave*64 + cf*16 + col;
          b[cf] = *(const bf16x8*)(Bs + n*128 + (((kk*4+q) ^ (n&7))*16));
        }
        #pragma unroll
        for (int rf=0;rf<4;rf++)
          #pragma unroll
          for (int cf=0;cf<4;cf++)
            acc[rf][cf] = __builtin_amdgcn_mfma_f32_16x16x32_bf16(a[rf], b[cf], acc[rf][cf], 0,0,0);
      }
    }
  }

  // epilogue: 2-phase fp32 transpose through LDS (reuse staging region)
  float* obuf = (float*)smem;   // 32 x 264 fp32 = 33792 B
  #pragma unroll
  for (int ph=0; ph<2; ++ph){
    __syncthreads();
    #pragma unroll
    for (int cf=0;cf<4;cf++){
      int o = wave*64 + cf*16 + col;
      float bA = be[eA*256 + o];
      float bB = be[eB*256 + o];
      #pragma unroll
      for (int rr=0;rr<2;rr++){
        int rf = ph*2 + rr;
        #pragma unroll
        for (int r=0;r<4;r++){
          int row = rf*16 + q*4 + r;
          float v = acc[rf][cf][r] + pAs[row]*bA + pBs[row]*bB;
          v = v > 0.f ? v : 0.01f*v;
          obuf[(row - ph*32)*264 + o] = v;
        }
      }
    }
    __syncthreads();
    #pragma unroll
    for (int j=0;j<8;j++){
      int idx = j*256 + tid;
      int lrow = idx>>6, c4 = idx&63;
      int row = ph*32 + lrow;
      int t = toks[row];
      if (t >= 0)
        *(f32x4*)&out[t*256 + c4*4] = *(const f32x4*)&obuf[lrow*264 + c4*4];
    }
  }
}

// ---------------------------------------------------------------------------
extern "C" void kernel_launch(void* const* d_in, const int* in_sizes, int n_in,
                              void* d_out, int out_size, void* d_ws, size_t ws_size,
                              hipStream_t stream)
{
  const float* x   = (const float*)d_in[0];
  const float* Wr1 = (const float*)d_in[1];
  const float* br1 = (const float*)d_in[2];
  const float* Wr2 = (const float*)d_in[3];
  const float* br2 = (const float*)d_in[4];
  const float* We  = (const float*)d_in[5];
  const float* be  = (const float*)d_in[6];
  float* out = (float*)d_out;

  // Workspace layout (non-overlapping, 16B-aligned; bug in R3 was pid/pAB overlap)
  char* ws = (char*)d_ws;
  ushort_t* Web      = (ushort_t*)ws;                 // [0,        2097152)
  ushort_t* W1b      = (ushort_t*)(ws + 2097152);     // [2097152,  2228224)
  ushort_t* W2h      = (ushort_t*)(ws + 2228224);     // [2228224,  2236416)
  ushort_t* W2l      = (ushort_t*)(ws + 2236416);     // [2236416,  2244608)
  int*      pid      = (int*)(ws + 2244608);          // [2244608,  2506752)
  float2*   pAB      = (float2*)(ws + 2506752);       // [2506752,  3031040)
  int*      sortedTok= (int*)(ws + 3031040);          // [3031040,  3293184)
  int*      fixTok   = (int*)(ws + 3293184);          // [3293184,  3555328)
  int*      cnt      = (int*)(ws + 3555328);          // 256 ints
  int*      fixCnt   = cnt + 256;                     // 1 int
  int*      cur      = cnt + 272;                     // 256 ints
  int*      off      = cnt + 528;                     // 257 ints
  int*      tileOff  = cnt + 785;                     // 257 ints

  hipMemsetAsync(cnt, 0, 257*sizeof(int), stream);
  k_prep    <<<4096, 256, 0, stream>>>(We, Wr1, Wr2, Web, W1b, W2h, W2l);
  r1r2_fused<<<1024, 256, 0, stream>>>(x, W1b, br1, W2h, W2l, br2, pid, pAB, fixCnt, fixTok);
  k_fixup   <<<1024, 256, 0, stream>>>(x, Wr1, br1, Wr2, br2, fixCnt, fixTok, pid, pAB);
  k_hist    <<<256,  256, 0, stream>>>(pid, cnt);
  k_scan    <<<1,    256, 0, stream>>>(cnt, cur, off, tileOff);
  k_scatter <<<256,  256, 0, stream>>>(pid, cur, sortedTok);
  k_expert  <<<1160, 256, 0, stream>>>(x, Web, be, off, tileOff, sortedTok, pAB, out);
}

// Round 5
// 331.758 us; speedup vs baseline: 1.4105x; 1.2596x over previous
//
#include <hip/hip_runtime.h>

typedef unsigned short ushort_t;
typedef __attribute__((ext_vector_type(8))) __bf16 bf16x8;
typedef __attribute__((ext_vector_type(4))) float f32x4;

#define MARGIN 1.5e-3f
#define FT 8   // fixup tokens per block

__device__ __forceinline__ float bf2f(ushort_t u){
  union { unsigned int i; float f; } v; v.i = ((unsigned int)u) << 16; return v.f;
}
__device__ __forceinline__ ushort_t f2bf(float f){
  union { float f; unsigned int i; } v; v.f = f;
  unsigned int x = v.i;
  return (ushort_t)((x + 0x7fffu + ((x >> 16) & 1u)) >> 16);
}
// async global->LDS, 16B per lane; LDS dest is wave-uniform base + lane*16
__device__ __forceinline__ void async_load16(const void* g, void* l){
  __builtin_amdgcn_global_load_lds((const __attribute__((address_space(1))) void*)g,
                                   (__attribute__((address_space(3))) void*)l, 16, 0, 0);
}

// ---------------------------------------------------------------------------
// prep: We -> bf16; Wr1 -> bf16; Wr2 -> bf16 hi + bf16 residual (lo).
// ---------------------------------------------------------------------------
__global__ __launch_bounds__(256) void k_prep(const float* __restrict__ We,
    const float* __restrict__ Wr1, const float* __restrict__ Wr2,
    ushort_t* __restrict__ Web, ushort_t* __restrict__ W1b,
    ushort_t* __restrict__ W2h, ushort_t* __restrict__ W2l)
{
  int idx = blockIdx.x*256 + threadIdx.x;
  if (idx < 1048576) Web[idx] = f2bf(We[idx]);
  if (idx < 65536)   W1b[idx] = f2bf(Wr1[idx]);
  if (idx < 4096){
    float w = Wr2[idx];
    ushort_t wh = f2bf(w);
    W2h[idx] = wh;
    W2l[idx] = f2bf(w - bf2f(wh));   // residual, captures next ~8 bits
  }
}

// ---------------------------------------------------------------------------
// Fused GEMM1 (bf16 MFMA) + logits MFMA (bf16 h x split-bf16 Wr2) + top2 +
// softmax + near-tie flagging. 64 tokens/block.
// ---------------------------------------------------------------------------
__global__ __launch_bounds__(256) void r1r2_fused(const float* __restrict__ x,
    const ushort_t* __restrict__ W1b, const float* __restrict__ br1,
    const ushort_t* __restrict__ W2h, const ushort_t* __restrict__ W2l,
    const float* __restrict__ br2,
    int* __restrict__ pid, float2* __restrict__ pAB,
    int* __restrict__ fixCnt, int* __restrict__ fixTok)
{
  __shared__ __align__(16) char smem[46336];
  ushort_t* As = (ushort_t*)smem;              // 64 x 72
  char*     Bs = smem + 9216;                  // 256 rows x 128B, XOR-swizzled
  ushort_t* hB = (ushort_t*)smem;              // 64 x 264 (reuse after K-loop)
  float*    lg = (float*)(smem + 41984);       // 64 x 17
  const int tid = threadIdx.x;
  const int wave = tid>>6, lane = tid&63, q = lane>>4, col = lane&15;
  const int tok0 = blockIdx.x*64;

  f32x4 acc[4][4];
  #pragma unroll
  for (int i=0;i<4;i++)
    #pragma unroll
    for (int j=0;j<4;j++) acc[i][j] = f32x4{0.f,0.f,0.f,0.f};

  for (int kc = 0; kc < 4; ++kc){
    const int kb = kc*64;
    __syncthreads();
    // B: 32KB via global_load_lds; wave stages rows [wave*64, wave*64+64)
    #pragma unroll
    for (int i=0;i<8;i++){
      int r0 = wave*64 + i*8;
      int grow = r0 + (lane>>3);
      int kc8 = (lane&7) ^ (grow&7);
      async_load16(W1b + grow*256 + kb + kc8*8, Bs + r0*128);
    }
    // A: x fp32 -> bf16
    #pragma unroll
    for (int j=0;j<2;j++){
      int idx = j*256 + tid, row = idx>>3, c8 = idx&7;
      f32x4 v0 = *(const f32x4*)&x[(tok0+row)*256 + kb + c8*8];
      f32x4 v1 = *(const f32x4*)&x[(tok0+row)*256 + kb + c8*8 + 4];
      union { uint4 u; ushort_t s[8]; } pk;
      pk.s[0]=f2bf(v0[0]); pk.s[1]=f2bf(v0[1]); pk.s[2]=f2bf(v0[2]); pk.s[3]=f2bf(v0[3]);
      pk.s[4]=f2bf(v1[0]); pk.s[5]=f2bf(v1[1]); pk.s[6]=f2bf(v1[2]); pk.s[7]=f2bf(v1[3]);
      *(uint4*)&As[row*72 + c8*8] = pk.u;
    }
    __syncthreads();
    #pragma unroll
    for (int kk=0;kk<2;kk++){
      bf16x8 a[4], b[4];
      #pragma unroll
      for (int rf=0;rf<4;rf++) a[rf] = *(const bf16x8*)&As[(rf*16+col)*72 + kk*32 + q*8];
      #pragma unroll
      for (int cf=0;cf<4;cf++){
        int n = wave*64 + cf*16 + col;
        b[cf] = *(const bf16x8*)(Bs + n*128 + (((kk*4+q) ^ (n&7))*16));
      }
      #pragma unroll
      for (int rf=0;rf<4;rf++)
        #pragma unroll
        for (int cf=0;cf<4;cf++)
          acc[rf][cf] = __builtin_amdgcn_mfma_f32_16x16x32_bf16(a[rf], b[cf], acc[rf][cf], 0,0,0);
    }
  }
  __syncthreads();
  // h = leaky(acc + br1) -> bf16 into hB
  {
    float br1v[4];
    #pragma unroll
    for (int cf=0;cf<4;cf++) br1v[cf] = br1[wave*64 + cf*16 + col];
    #pragma unroll
    for (int rf=0;rf<4;rf++)
      #pragma unroll
      for (int cf=0;cf<4;cf++){
        int o = wave*64 + cf*16 + col;
        #pragma unroll
        for (int r=0;r<4;r++){
          int row = rf*16 + q*4 + r;
          float p = acc[rf][cf][r] + br1v[cf];
          p = p > 0.f ? p : 0.01f*p;
          hB[row*264 + o] = f2bf(p);
        }
      }
  }
  __syncthreads();
  // logits[64x16] = h @ Wr2^T via MFMA; wave handles its 16-token m-tile
  {
    f32x4 acc2 = f32x4{0.f,0.f,0.f,0.f};
    #pragma unroll
    for (int c2=0;c2<8;c2++){
      bf16x8 a2 = *(const bf16x8*)&hB[(wave*16+col)*264 + c2*32 + q*8];
      bf16x8 bh = *(const bf16x8*)&W2h[col*256 + c2*32 + q*8];
      bf16x8 bl = *(const bf16x8*)&W2l[col*256 + c2*32 + q*8];
      acc2 = __builtin_amdgcn_mfma_f32_16x16x32_bf16(a2, bh, acc2, 0,0,0);
      acc2 = __builtin_amdgcn_mfma_f32_16x16x32_bf16(a2, bl, acc2, 0,0,0);
    }
    #pragma unroll
    for (int r=0;r<4;r++) lg[(wave*16 + q*4 + r)*17 + col] = acc2[r];
  }
  __syncthreads();
  if (tid < 64){
    const int tok = tok0 + tid;
    float v[16];
    #pragma unroll
    for (int e=0;e<16;e++) v[e] = lg[tid*17 + e] + br2[e];
    float best=-3.4e38f, sec=-3.4e38f, thr=-3.4e38f; int b1=0, b2=0;
    #pragma unroll
    for (int e=0;e<16;e++){
      float val = v[e];
      if (val > best){ thr=sec; sec=best; b2=b1; best=val; b1=e; }
      else if (val > sec){ thr=sec; sec=val; b2=e; }
      else if (val > thr){ thr=val; }
    }
    float ex = expf(sec - best);
    float s = 1.f + ex;
    float p1 = 1.f/s, p2 = ex/s;
    int eA = b1 < b2 ? b1 : b2;
    int eB = b1 < b2 ? b2 : b1;
    float pA = b1 < b2 ? p1 : p2;
    float pB = b1 < b2 ? p2 : p1;
    pid[tok] = eA*16 + eB;
    pAB[tok] = make_float2(pA, pB);
    if (sec - thr < MARGIN){
      int slot = atomicAdd(fixCnt, 1);
      fixTok[slot] = tok;
    }
  }
}

// ---------------------------------------------------------------------------
// fp64 exact router recompute for near-tie tokens.
// R5 rewrite: 8 tokens per block (Wr1 read ONCE per block for all 8 — 8x L2
// traffic cut), layer2 uses 128 threads, no serial per-token phases.
// ---------------------------------------------------------------------------
__global__ __launch_bounds__(256) void k_fixup(const float* __restrict__ x,
    const float* __restrict__ Wr1, const float* __restrict__ br1,
    const float* __restrict__ Wr2, const float* __restrict__ br2,
    const int* __restrict__ fixCnt, const int* __restrict__ fixTok,
    int* __restrict__ pid, float2* __restrict__ pAB)
{
  __shared__ float  xs[FT][256];     // 8 KB
  __shared__ double hs[FT*256];      // 16 KB
  __shared__ double lgs[FT][16];
  const int tid = threadIdx.x;
  const int n = *fixCnt;
  for (int base = blockIdx.x*FT; base < n; base += gridDim.x*FT){
    const int nt = min(FT, n - base);
    __syncthreads();
    for (int i = tid; i < nt*256; i += 256){
      int t = i >> 8, c = i & 255;
      xs[t][c] = x[fixTok[base + t]*256 + c];
    }
    __syncthreads();
    // layer 1: thread o computes h[t][o] for all FT tokens; Wr1 row read once
    {
      const int o = tid;
      double acc[FT];
      #pragma unroll
      for (int t=0;t<FT;t++) acc[t] = 0.0;
      for (int k=0;k<64;k++){
        f32x4 w = *(const f32x4*)&Wr1[o*256 + k*4];
        double w0=(double)w[0], w1=(double)w[1], w2=(double)w[2], w3=(double)w[3];
        #pragma unroll
        for (int t=0;t<FT;t++){
          acc[t] += (double)xs[t][k*4+0]*w0;
          acc[t] += (double)xs[t][k*4+1]*w1;
          acc[t] += (double)xs[t][k*4+2]*w2;
          acc[t] += (double)xs[t][k*4+3]*w3;
        }
      }
      double b = (double)br1[o];
      #pragma unroll
      for (int t=0;t<FT;t++){
        double v = acc[t] + b;
        hs[t*256 + o] = v > 0.0 ? v : 0.01*v;
      }
    }
    __syncthreads();
    // layer 2: 128 threads, (t,e) = (tid>>4, tid&15)
    if (tid < FT*16){
      const int t = tid >> 4, e = tid & 15;
      double a0=0,a1=0,a2=0,a3=0;
      for (int k=0;k<64;k++){
        f32x4 w = *(const f32x4*)&Wr2[e*256 + k*4];
        a0 += hs[t*256 + k*4+0]*(double)w[0];
        a1 += hs[t*256 + k*4+1]*(double)w[1];
        a2 += hs[t*256 + k*4+2]*(double)w[2];
        a3 += hs[t*256 + k*4+3]*(double)w[3];
      }
      lgs[t][e] = ((a0+a1)+(a2+a3)) + (double)br2[e];
    }
    __syncthreads();
    if (tid < nt){
      const int tok = fixTok[base + tid];
      double best=-1e300, sec=-1e300; int b1=0, b2=0;
      #pragma unroll
      for (int e=0;e<16;e++){
        double val = lgs[tid][e];
        if (val > best){ sec=best; b2=b1; best=val; b1=e; }
        else if (val > sec){ sec=val; b2=e; }
      }
      double ex = exp(sec - best);
      double s = 1.0 + ex;
      double p1 = 1.0/s, p2 = ex/s;
      int eA = b1 < b2 ? b1 : b2;
      int eB = b1 < b2 ? b2 : b1;
      float pA = (float)(b1 < b2 ? p1 : p2);
      float pB = (float)(b1 < b2 ? p2 : p1);
      pid[tok] = eA*16 + eB;
      pAB[tok] = make_float2(pA, pB);
    }
  }
}

__global__ __launch_bounds__(256) void k_hist(const int* __restrict__ pid, int* __restrict__ cnt)
{
  __shared__ int hc[256];
  const int tid = threadIdx.x;
  hc[tid] = 0; __syncthreads();
  atomicAdd(&hc[pid[blockIdx.x*256 + tid]], 1);
  __syncthreads();
  if (hc[tid]) atomicAdd(&cnt[tid], hc[tid]);
}

__global__ __launch_bounds__(256) void k_scan(int* __restrict__ cnt, int* __restrict__ cur,
    int* __restrict__ off, int* __restrict__ tileOff)
{
  __shared__ int sc[256];
  const int tid = threadIdx.x;
  int c = cnt[tid];
  sc[tid] = c; __syncthreads();
  for (int s=1;s<256;s<<=1){ int v = (tid>=s)? sc[tid-s]:0; __syncthreads(); sc[tid]+=v; __syncthreads(); }
  int inc = sc[tid];
  off[tid] = inc - c;
  cur[tid] = inc - c;
  if (tid==255) off[256] = inc;
  int tc = (c+63)>>6;
  __syncthreads();
  sc[tid] = tc; __syncthreads();
  for (int s=1;s<256;s<<=1){ int v = (tid>=s)? sc[tid-s]:0; __syncthreads(); sc[tid]+=v; __syncthreads(); }
  tileOff[tid] = sc[tid] - tc;
  if (tid==255) tileOff[256] = sc[tid];
}

__global__ __launch_bounds__(256) void k_scatter(const int* __restrict__ pid,
    int* __restrict__ cur, int* __restrict__ sortedTok)
{
  int b = blockIdx.x*256 + threadIdx.x;
  int p = pid[b];
  int slot = atomicAdd(&cur[p], 1);
  sortedTok[slot] = b;
}

// ---------------------------------------------------------------------------
// Expert pair GEMM: bf16 MFMA, probs folded into A staging, B tiles via
// global_load_lds (XOR-swizzled), fp32 output via 2-phase LDS transpose.
// ---------------------------------------------------------------------------
__global__ __launch_bounds__(256) void k_expert(const float* __restrict__ x,
    const ushort_t* __restrict__ Web, const float* __restrict__ be,
    const int* __restrict__ off, const int* __restrict__ tileOff,
    const int* __restrict__ sortedTok, const float2* __restrict__ pAB,
    float* __restrict__ out)
{
  const int totTiles = tileOff[256];
  const int bid = blockIdx.x;
  if (bid >= totTiles) return;
  __shared__ __align__(16) char smem[41984];
  ushort_t* As = (ushort_t*)smem;          // 64 x 72
  char*     Bs = smem + 9216;              // 256 rows x 128B, swizzled
  __shared__ int toks[64];
  __shared__ float pAs[64], pBs[64];
  __shared__ int sh_p;
  const int tid = threadIdx.x;
  if (tid == 0){
    int lo=0, hi=255;
    while (lo < hi){ int mid=(lo+hi+1)>>1; if (tileOff[mid] <= bid) lo=mid; else hi=mid-1; }
    sh_p = lo;
  }
  __syncthreads();
  const int p = sh_p;
  const int tstart = off[p] + (bid - tileOff[p])*64;
  const int nt = min(64, off[p+1] - tstart);
  if (tid < 64){
    if (tid < nt){
      int t = sortedTok[tstart + tid];
      toks[tid] = t;
      float2 ab = pAB[t];
      pAs[tid] = ab.x; pBs[tid] = ab.y;
    } else { toks[tid] = -1; pAs[tid]=0.f; pBs[tid]=0.f; }
  }
  const int wave = tid>>6, lane = tid&63, q = lane>>4, col = lane&15;
  const int eA = p >> 4, eB = p & 15;
  f32x4 acc[4][4];
  #pragma unroll
  for (int i=0;i<4;i++)
    #pragma unroll
    for (int j=0;j<4;j++) acc[i][j] = f32x4{0.f,0.f,0.f,0.f};

  for (int pass=0; pass<2; ++pass){
    const ushort_t* W = Web + (pass ? eB : eA)*65536;
    for (int kc=0; kc<4; ++kc){
      const int kb = kc*64;
      __syncthreads();
      #pragma unroll
      for (int i=0;i<8;i++){
        int r0 = wave*64 + i*8;
        int grow = r0 + (lane>>3);
        int kc8 = (lane&7) ^ (grow&7);
        async_load16(W + grow*256 + kb + kc8*8, Bs + r0*128);
      }
      #pragma unroll
      for (int j=0;j<2;j++){
        int idx = j*256 + tid, row = idx>>3, c8 = idx&7;
        int t = toks[row];
        uint4 val = make_uint4(0u,0u,0u,0u);
        if (t >= 0){
          float ps = pass ? pBs[row] : pAs[row];
          f32x4 v0 = *(const f32x4*)&x[t*256 + kb + c8*8];
          f32x4 v1 = *(const f32x4*)&x[t*256 + kb + c8*8 + 4];
          union { uint4 u; ushort_t s[8]; } pk;
          pk.s[0]=f2bf(v0[0]*ps); pk.s[1]=f2bf(v0[1]*ps); pk.s[2]=f2bf(v0[2]*ps); pk.s[3]=f2bf(v0[3]*ps);
          pk.s[4]=f2bf(v1[0]*ps); pk.s[5]=f2bf(v1[1]*ps); pk.s[6]=f2bf(v1[2]*ps); pk.s[7]=f2bf(v1[3]*ps);
          val = pk.u;
        }
        *(uint4*)&As[row*72 + c8*8] = val;
      }
      __syncthreads();
      #pragma unroll
      for (int kk=0;kk<2;kk++){
        bf16x8 a[4], b[4];
        #pragma unroll
        for (int rf=0;rf<4;rf++) a[rf] = *(const bf16x8*)&As[(rf*16+col)*72 + kk*32 + q*8];
        #pragma unroll
        for (int cf=0;cf<4;cf++){
          int n = wave*64 + cf*16 + col;
          b[cf] = *(const bf16x8*)(Bs + n*128 + (((kk*4+q) ^ (n&7))*16));
        }
        #pragma unroll
        for (int rf=0;rf<4;rf++)
          #pragma unroll
          for (int cf=0;cf<4;cf++)
            acc[rf][cf] = __builtin_amdgcn_mfma_f32_16x16x32_bf16(a[rf], b[cf], acc[rf][cf], 0,0,0);
      }
    }
  }

  // epilogue: 2-phase fp32 transpose through LDS (reuse staging region)
  float* obuf = (float*)smem;   // 32 x 264 fp32 = 33792 B
  #pragma unroll
  for (int ph=0; ph<2; ++ph){
    __syncthreads();
    #pragma unroll
    for (int cf=0;cf<4;cf++){
      int o = wave*64 + cf*16 + col;
      float bA = be[eA*256 + o];
      float bB = be[eB*256 + o];
      #pragma unroll
      for (int rr=0;rr<2;rr++){
        int rf = ph*2 + rr;
        #pragma unroll
        for (int r=0;r<4;r++){
          int row = rf*16 + q*4 + r;
          float v = acc[rf][cf][r] + pAs[row]*bA + pBs[row]*bB;
          v = v > 0.f ? v : 0.01f*v;
          obuf[(row - ph*32)*264 + o] = v;
        }
      }
    }
    __syncthreads();
    #pragma unroll
    for (int j=0;j<8;j++){
      int idx = j*256 + tid;
      int lrow = idx>>6, c4 = idx&63;
      int row = ph*32 + lrow;
      int t = toks[row];
      if (t >= 0)
        *(f32x4*)&out[t*256 + c4*4] = *(const f32x4*)&obuf[lrow*264 + c4*4];
    }
  }
}

// ---------------------------------------------------------------------------
extern "C" void kernel_launch(void* const* d_in, const int* in_sizes, int n_in,
                              void* d_out, int out_size, void* d_ws, size_t ws_size,
                              hipStream_t stream)
{
  const float* x   = (const float*)d_in[0];
  const float* Wr1 = (const float*)d_in[1];
  const float* br1 = (const float*)d_in[2];
  const float* Wr2 = (const float*)d_in[3];
  const float* br2 = (const float*)d_in[4];
  const float* We  = (const float*)d_in[5];
  const float* be  = (const float*)d_in[6];
  float* out = (float*)d_out;

  // Workspace layout (non-overlapping, 16B-aligned)
  char* ws = (char*)d_ws;
  ushort_t* Web      = (ushort_t*)ws;                 // [0,        2097152)
  ushort_t* W1b      = (ushort_t*)(ws + 2097152);     // [2097152,  2228224)
  ushort_t* W2h      = (ushort_t*)(ws + 2228224);     // [2228224,  2236416)
  ushort_t* W2l      = (ushort_t*)(ws + 2236416);     // [2236416,  2244608)
  int*      pid      = (int*)(ws + 2244608);          // [2244608,  2506752)
  float2*   pAB      = (float2*)(ws + 2506752);       // [2506752,  3031040)
  int*      sortedTok= (int*)(ws + 3031040);          // [3031040,  3293184)
  int*      fixTok   = (int*)(ws + 3293184);          // [3293184,  3555328)
  int*      cnt      = (int*)(ws + 3555328);          // 256 ints
  int*      fixCnt   = cnt + 256;                     // 1 int
  int*      cur      = cnt + 272;                     // 256 ints
  int*      off      = cnt + 528;                     // 257 ints
  int*      tileOff  = cnt + 785;                     // 257 ints

  hipMemsetAsync(cnt, 0, 257*sizeof(int), stream);
  k_prep    <<<4096, 256, 0, stream>>>(We, Wr1, Wr2, Web, W1b, W2h, W2l);
  r1r2_fused<<<1024, 256, 0, stream>>>(x, W1b, br1, W2h, W2l, br2, pid, pAB, fixCnt, fixTok);
  k_fixup   <<<512,  256, 0, stream>>>(x, Wr1, br1, Wr2, br2, fixCnt, fixTok, pid, pAB);
  k_hist    <<<256,  256, 0, stream>>>(pid, cnt);
  k_scan    <<<1,    256, 0, stream>>>(cnt, cur, off, tileOff);
  k_scatter <<<256,  256, 0, stream>>>(pid, cur, sortedTok);
  k_expert  <<<1160, 256, 0, stream>>>(x, Web, be, off, tileOff, sortedTok, pAB, out);
}